// Round 17
// baseline (456.657 us; speedup 1.0000x reference)
//
#include <hip/hip_runtime.h>

typedef float f2 __attribute__((ext_vector_type(2)));
typedef float f4 __attribute__((ext_vector_type(4)));

#define TT 2048
#define BB 512
#define II 10
#define HH 20
#define CH 32                 // consumer steps per barrier / history depth
#define RS 64                 // ring slots = 2 chunks (double buffer)
#define NCHUNK (TT / CH)      // 64

#define LOG2E 1.44269504088896340736f

__device__ __forceinline__ float fexp2(float x) {
#if __has_builtin(__builtin_amdgcn_exp2f)
    return __builtin_amdgcn_exp2f(x);
#else
    return exp2f(x);
#endif
}

// One block = 2 waves per SAMPLE (R16 structure + producer-side output dump).
// Wave 0 (consumer): lanes 0..19 scan FORWARD, lanes 32..51 scan REVERSE
//   (lane owns hidden unit j of its dir; all 4 gates per lane). Per step:
//   rec dots from hb -> ring xp applied LATE -> product-rcp activations
//   (4 exp2 + 3 rcp) with cs = -2log2e*c via fma -> h -> ring prefetch ->
//   predicated ds_write h into hstage[chunk&1] -> 5x ds_read_b128 broadcast.
//   ZERO global stores in the consumer: its barrier drain is lgkm-only.
// Wave 1 (producer): per chunk k: dump chunk k-1's hstage buffer to HBM
//   (20 ds_read + global_store per lane, both dirs), then produce chunk k+1's
//   xproj into ring[64][64]. Its stores retire during the next whole chunk,
//   so no wave ever waits on a store drain.
// hstage[2][32][40]: row = [fwd units 0..19 | rev units 0..19], 160B stride.
__global__ __launch_bounds__(128, 1) void lstm_bidir(
    const float* __restrict__ x,
    const float* __restrict__ w_ih_f, const float* __restrict__ w_hh_f,
    const float* __restrict__ b_ih_f, const float* __restrict__ b_hh_f,
    const float* __restrict__ w_ih_r, const float* __restrict__ w_hh_r,
    const float* __restrict__ b_ih_r, const float* __restrict__ b_hh_r,
    float* __restrict__ out)
{
    const int tid  = threadIdx.x;
    const int wid  = tid >> 6;     // 0 = consumer, 1 = producer
    const int lane = tid & 63;
    const int s    = blockIdx.x;   // batch sample

    const int  dirh  = lane >> 5;          // 0 = forward half, 1 = reverse half
    const int  hl    = lane & 31;
    const bool valid = (hl < HH);
    const int  j     = valid ? hl : (HH - 1);   // clamp keeps loads in-bounds

    const float* __restrict__ w_ih = dirh ? w_ih_r : w_ih_f;
    const float* __restrict__ w_hh = dirh ? w_hh_r : w_hh_f;
    const float* __restrict__ b_ih = dirh ? b_ih_r : b_ih_f;
    const float* __restrict__ b_hh = dirh ? b_hh_r : b_hh_f;

    const int t0    = dirh ? (TT - 1) : 0;
    const int xstep = dirh ? -(BB * II) : (BB * II);
    const int xbase = (t0 * BB + s) * II;

    // Row scale per gate (i,f,g,o): sigmoid rows -log2e, tanh row -2log2e.
    const float gsc[4] = { -LOG2E, -LOG2E, -2.0f * LOG2E, -LOG2E };

    __shared__ f4    ring[RS][64];           // xproj ring: [slot][lane]
    __shared__ float hstage[2][CH][2 * HH];  // h history: [buf][step][fwd20|rev20]

    if (wid == 1) {
        // ---------------- producer wave: xproj + output dump ----------------
        f2 wih[4][5];
        float bs[4];
#pragma unroll
        for (int g = 0; g < 4; ++g) {
            const int r = g * HH + j;
#pragma unroll
            for (int k = 0; k < 5; ++k) {
                f2 w = *(const f2*)(w_ih + r * II + 2 * k);
                wih[g][k] = w * gsc[g];
            }
            bs[g] = (b_ih[r] + b_hh[r]) * gsc[g];
        }

        auto produce8 = [&](int base) {
            f2 xb[8][5];
#pragma unroll
            for (int i = 0; i < 8; ++i) {
                int u = base + i; if (u > TT - 1) u = TT - 1;   // in-bounds clamp
                const float* px = x + (xbase + u * xstep);
#pragma unroll
                for (int k = 0; k < 5; ++k) xb[i][k] = *(const f2*)(px + 2 * k);
            }
#pragma unroll
            for (int i = 0; i < 8; ++i) {
                const int u = base + i;
                if (u < TT) {
                    f4 xp;
#pragma unroll
                    for (int g = 0; g < 4; ++g) {
                        f2 p = {bs[g], 0.f};
#pragma unroll
                        for (int k = 0; k < 5; ++k) p += wih[g][k] * xb[i][k];
                        xp[g] = p[0] + p[1];
                    }
                    ring[u & (RS - 1)][lane] = xp;
                }
            }
        };

        // Dump chunk c's staged h block (2 dirs x 32 t x 20 j = 1280 elems,
        // 20 per lane). Precompute per-q invariants.
        int tdq[20], remq[20], dirq[20], jdq[20];
#pragma unroll
        for (int q = 0; q < 20; ++q) {
            const int idx = q * 64 + lane;        // 0..1279
            tdq[q]  = idx / (2 * HH);             // 0..31
            remq[q] = idx - tdq[q] * (2 * HH);    // 0..39
            dirq[q] = remq[q] / HH;               // 0 = fwd, 1 = rev
            jdq[q]  = remq[q] - dirq[q] * HH;     // 0..19
        }

        auto dump = [&](int c) {
            const int buf = c & 1;
#pragma unroll
            for (int q = 0; q < 20; ++q) {
                const int tg   = c * CH + tdq[q];
                const int trow = dirq[q] ? (TT - 1 - tg) : tg;
                out[(trow * BB + s) * (2 * HH) + dirq[q] * HH + jdq[q]] =
                    hstage[buf][tdq[q]][remq[q]];
            }
        };

        produce8(0);  produce8(8);     // prefill chunk 0
        produce8(16); produce8(24);
        for (int chunk = 0; chunk < NCHUNK; ++chunk) {
            __syncthreads();
            if (chunk > 0) dump(chunk - 1);
            const int base = (chunk + 1) * CH;   // fill next chunk's half
            produce8(base);      produce8(base + 8);
            produce8(base + 16); produce8(base + 24);
        }
        __syncthreads();
        dump(NCHUNK - 1);
    } else {
        // ---------------- consumer wave (two scans, one per half) ----------------
        __builtin_amdgcn_s_setprio(1);

        f2 whh[4][10];
#pragma unroll
        for (int g = 0; g < 4; ++g) {
            const int r = g * HH + j;
#pragma unroll
            for (int k = 0; k < 10; ++k) {
                f2 w = *(const f2*)(w_hh + r * HH + 2 * k);
                whh[g][k] = w * gsc[g];
            }
        }

        const int hpos  = dirh * HH + j;      // own write slot in an hstage row
        const int hboff = dirh * HH;          // own half's 20-float segment

        const float K2 = 2.0f * LOG2E;

        f4 hb[5];
#pragma unroll
        for (int k = 0; k < 5; ++k) hb[k] = f4{0.f, 0.f, 0.f, 0.f};

        float cs = 0.0f;    // cs = -2*log2e * c  (so e^{-2c} = 2^cs)
        int t = 0;

        for (int chunk = 0; chunk < NCHUNK; ++chunk) {
            __syncthreads();
            const int buf = chunk & 1;
            f4 xp = ring[t & (RS - 1)][lane];   // first step of chunk
#pragma unroll 4
            for (int i = 0; i < CH; ++i, ++t) {
                // ---- recurrent dots: 4 gates x 10 pk-FMA (hb-dependent only) ----
                f2 a0[4], a1[4];
#pragma unroll
                for (int g = 0; g < 4; ++g) { a0[g] = f2{0.f, 0.f}; a1[g] = f2{0.f, 0.f}; }
#pragma unroll
                for (int k = 0; k < 5; ++k) {
                    const f4 hv = hb[k];
                    f2 lo; lo[0] = hv[0]; lo[1] = hv[1];
                    f2 hi; hi[0] = hv[2]; hi[1] = hv[3];
#pragma unroll
                    for (int g = 0; g < 4; ++g) {
                        a0[g] += whh[g][2 * k]     * lo;
                        a1[g] += whh[g][2 * k + 1] * hi;
                    }
                }
                // xp applied LATE: ring ds_read gets ~80cy of rec-FMA slack.
                float u[4];
#pragma unroll
                for (int g = 0; g < 4; ++g) {
                    const f2 a = a0[g] + a1[g];
                    u[g] = (xp[g] + a[0]) + a[1];   // pre-scaled: exp2-ready
                }

                // ---- activations, product-rcp + cs fold (4 exp2 + 3 rcp) ----
                const float ei = fexp2(u[0]);
                const float ef = fexp2(u[1]);
                const float eg = fexp2(u[2]);
                const float eo = fexp2(u[3]);
                const float fg = __builtin_amdgcn_rcpf(1.0f + ef);           // sigma(v_f)
                const float r1 = __builtin_amdgcn_rcpf((1.0f + ei) * (1.0f + eg));
                const float km = __builtin_fmaf(K2, eg, -K2) * r1;  // -2log2e * i*tanh(v_g)
                cs = __builtin_fmaf(fg, cs, km);                    // -2log2e * c
                const float ec = fexp2(cs);                         // e^{-2c}
                const float h  = (1.0f - ec) *
                    __builtin_amdgcn_rcpf((1.0f + eo) * (1.0f + ec));        // o*tanh(c)

                // ---- ring prefetch FIRST (LDS queue: [ring, write, hb x5]) ----
                xp = ring[(t + 1) & (RS - 1)][lane];   // last-iter race benign

                // ---- stage h (predicated; consumer does NO global stores) ----
                if (valid) hstage[buf][i][hpos] = h;
                __builtin_amdgcn_wave_barrier();

                // ---- broadcast read of own half's 20 h (same-wave LDS in-order) ----
#pragma unroll
                for (int k = 0; k < 5; ++k)
                    hb[k] = *(const f4*)&hstage[buf][i][hboff + 4 * k];
            }
        }
        __syncthreads();   // release producer's final dump
    }
}

extern "C" void kernel_launch(void* const* d_in, const int* in_sizes, int n_in,
                              void* d_out, int out_size, void* d_ws, size_t ws_size,
                              hipStream_t stream) {
    const float* xp     = (const float*)d_in[0];
    const float* w_ih_f = (const float*)d_in[1];
    const float* w_hh_f = (const float*)d_in[2];
    const float* b_ih_f = (const float*)d_in[3];
    const float* b_hh_f = (const float*)d_in[4];
    const float* w_ih_r = (const float*)d_in[5];
    const float* w_hh_r = (const float*)d_in[6];
    const float* b_ih_r = (const float*)d_in[7];
    const float* b_hh_r = (const float*)d_in[8];
    float* outp = (float*)d_out;

    hipLaunchKernelGGL(lstm_bidir, dim3(512), dim3(128), 0, stream,
                       xp, w_ih_f, w_hh_f, b_ih_f, b_hh_f,
                       w_ih_r, w_hh_r, b_ih_r, b_hh_r, outp);
}

// Round 18
// 447.697 us; speedup vs baseline: 1.0200x; 1.0200x over previous
//
#include <hip/hip_runtime.h>

typedef float f2 __attribute__((ext_vector_type(2)));
typedef float f4 __attribute__((ext_vector_type(4)));

#define TT 2048
#define BB 512
#define II 10
#define HH 20
#define CH 32                 // consumer steps per barrier / history depth
#define RS 64                 // ring slots = 2 chunks (double buffer)
#define NCHUNK (TT / CH)      // 64

#define LOG2E 1.44269504088896340736f

__device__ __forceinline__ float fexp2(float x) {
#if __has_builtin(__builtin_amdgcn_exp2f)
    return __builtin_amdgcn_exp2f(x);
#else
    return exp2f(x);
#endif
}

// One block = 2 waves per SAMPLE (R16 structure; dump moved across the barrier).
// Wave 0 (consumer): lanes 0..19 scan FORWARD, lanes 32..51 scan REVERSE
//   (lane owns hidden unit j of its dir; all 4 gates per lane). Per step:
//   rec dots from hb -> ring xp applied LATE -> product-rcp activations
//   (4 exp2 + 3 rcp) with cs = -2log2e*c via fma -> h -> ring prefetch ->
//   unconditional ds_write h into hstage[chunk&1] -> 5x ds_read broadcast.
//   The HBM dump of chunk k-1 happens right AFTER barrier k (double-buffered
//   hstage), so its stores retire during the whole next chunk and the
//   consumer never drains vmcnt at a barrier (R16 paid ~300-600cy/chunk).
//   Clamp lanes (hl 20..31) compute values identical to lane j=19, so the
//   hstage write is unconditional (benign same-value race, no exec flip).
// Wave 1 (producer): xproj[t] = b + W_ih x[t] (pre-scaled) into ring[64][64],
//   double-buffered halves, 1 __syncthreads per 32 steps (identical to R16).
__global__ __launch_bounds__(128, 1) void lstm_bidir(
    const float* __restrict__ x,
    const float* __restrict__ w_ih_f, const float* __restrict__ w_hh_f,
    const float* __restrict__ b_ih_f, const float* __restrict__ b_hh_f,
    const float* __restrict__ w_ih_r, const float* __restrict__ w_hh_r,
    const float* __restrict__ b_ih_r, const float* __restrict__ b_hh_r,
    float* __restrict__ out)
{
    const int tid  = threadIdx.x;
    const int wid  = tid >> 6;     // 0 = consumer, 1 = producer
    const int lane = tid & 63;
    const int s    = blockIdx.x;   // batch sample

    const int  dirh  = lane >> 5;          // 0 = forward half, 1 = reverse half
    const int  hl    = lane & 31;
    const bool valid = (hl < HH);
    const int  j     = valid ? hl : (HH - 1);   // clamp keeps loads in-bounds

    const float* __restrict__ w_ih = dirh ? w_ih_r : w_ih_f;
    const float* __restrict__ w_hh = dirh ? w_hh_r : w_hh_f;
    const float* __restrict__ b_ih = dirh ? b_ih_r : b_ih_f;
    const float* __restrict__ b_hh = dirh ? b_hh_r : b_hh_f;

    const int t0    = dirh ? (TT - 1) : 0;
    const int xstep = dirh ? -(BB * II) : (BB * II);
    const int ostep = dirh ? -(BB * 2 * HH) : (BB * 2 * HH);
    const int xbase = (t0 * BB + s) * II;

    // Row scale per gate (i,f,g,o): sigmoid rows -log2e, tanh row -2log2e.
    const float gsc[4] = { -LOG2E, -LOG2E, -2.0f * LOG2E, -LOG2E };

    __shared__ f4    ring[RS][64];           // xproj ring: [slot][lane]
    __shared__ float hstage[2][CH][2 * HH];  // [buf][step][fwd20|rev20]

    if (wid == 1) {
        // ---------------- producer wave (identical to R16) ----------------
        f2 wih[4][5];
        float bs[4];
#pragma unroll
        for (int g = 0; g < 4; ++g) {
            const int r = g * HH + j;
#pragma unroll
            for (int k = 0; k < 5; ++k) {
                f2 w = *(const f2*)(w_ih + r * II + 2 * k);
                wih[g][k] = w * gsc[g];
            }
            bs[g] = (b_ih[r] + b_hh[r]) * gsc[g];
        }

        auto produce8 = [&](int base) {
            f2 xb[8][5];
#pragma unroll
            for (int i = 0; i < 8; ++i) {
                int u = base + i; if (u > TT - 1) u = TT - 1;   // in-bounds clamp
                const float* px = x + (xbase + u * xstep);
#pragma unroll
                for (int k = 0; k < 5; ++k) xb[i][k] = *(const f2*)(px + 2 * k);
            }
#pragma unroll
            for (int i = 0; i < 8; ++i) {
                const int u = base + i;
                if (u < TT) {
                    f4 xp;
#pragma unroll
                    for (int g = 0; g < 4; ++g) {
                        f2 p = {bs[g], 0.f};
#pragma unroll
                        for (int k = 0; k < 5; ++k) p += wih[g][k] * xb[i][k];
                        xp[g] = p[0] + p[1];
                    }
                    ring[u & (RS - 1)][lane] = xp;
                }
            }
        };

        produce8(0);  produce8(8);     // prefill chunk 0
        produce8(16); produce8(24);
        for (int chunk = 0; chunk < NCHUNK; ++chunk) {
            __syncthreads();
            const int base = (chunk + 1) * CH;   // fill next chunk's half
            produce8(base);      produce8(base + 8);
            produce8(base + 16); produce8(base + 24);
        }
    } else {
        // ---------------- consumer wave (two scans, one per half) ----------------
        __builtin_amdgcn_s_setprio(1);

        f2 whh[4][10];
#pragma unroll
        for (int g = 0; g < 4; ++g) {
            const int r = g * HH + j;
#pragma unroll
            for (int k = 0; k < 10; ++k) {
                f2 w = *(const f2*)(w_hh + r * HH + 2 * k);
                whh[g][k] = w * gsc[g];
            }
        }

        const int hpos  = dirh * HH + j;      // own write slot in an hstage row
        const int hboff = dirh * HH;          // own half's 20-float segment

        // Dump mapping: per half, 640 elements (32 t x 20 j) over 32 lanes x 20.
        const int obase = (t0 * BB + s) * (2 * HH) + dirh * HH;
        int offd[20], lds_d[20];
#pragma unroll
        for (int q = 0; q < 20; ++q) {
            const int idx = q * 32 + hl;          // 0..639 within own half
            const int td  = idx / HH;             // 0..31
            const int jd  = idx - td * HH;        // 0..19
            offd[q]  = obase + td * ostep + jd;
            lds_d[q] = td * (2 * HH) + dirh * HH + jd;
        }

        const float K2 = 2.0f * LOG2E;

        f4 hb[5];
#pragma unroll
        for (int k = 0; k < 5; ++k) hb[k] = f4{0.f, 0.f, 0.f, 0.f};

        float cs = 0.0f;    // cs = -2*log2e * c  (so e^{-2c} = 2^cs)
        int t = 0;

        for (int chunk = 0; chunk < NCHUNK; ++chunk) {
            __syncthreads();
            const int buf = chunk & 1;

            // ---- dump chunk-1's buffer NOW: stores get a whole chunk to retire
            //      before the next barrier (no vmcnt drain on the scan path) ----
            if (chunk > 0) {
                const float* hsrc = &hstage[buf ^ 1][0][0];
#pragma unroll
                for (int q = 0; q < 20; ++q) {
                    out[offd[q]] = hsrc[lds_d[q]];
                    offd[q] += CH * ostep;
                }
            }

            f4 xp = ring[t & (RS - 1)][lane];   // first step of chunk
#pragma unroll 4
            for (int i = 0; i < CH; ++i, ++t) {
                // ---- recurrent dots: 4 gates x 10 pk-FMA (hb-dependent only) ----
                f2 a0[4], a1[4];
#pragma unroll
                for (int g = 0; g < 4; ++g) { a0[g] = f2{0.f, 0.f}; a1[g] = f2{0.f, 0.f}; }
#pragma unroll
                for (int k = 0; k < 5; ++k) {
                    const f4 hv = hb[k];
                    f2 lo; lo[0] = hv[0]; lo[1] = hv[1];
                    f2 hi; hi[0] = hv[2]; hi[1] = hv[3];
#pragma unroll
                    for (int g = 0; g < 4; ++g) {
                        a0[g] += whh[g][2 * k]     * lo;
                        a1[g] += whh[g][2 * k + 1] * hi;
                    }
                }
                // xp applied LATE: ring ds_read gets ~80cy of rec-FMA slack.
                float u[4];
#pragma unroll
                for (int g = 0; g < 4; ++g) {
                    const f2 a = a0[g] + a1[g];
                    u[g] = (xp[g] + a[0]) + a[1];   // pre-scaled: exp2-ready
                }

                // ---- activations, product-rcp + cs fold (4 exp2 + 3 rcp) ----
                const float ei = fexp2(u[0]);
                const float ef = fexp2(u[1]);
                const float eg = fexp2(u[2]);
                const float eo = fexp2(u[3]);
                const float fg = __builtin_amdgcn_rcpf(1.0f + ef);           // sigma(v_f)
                const float r1 = __builtin_amdgcn_rcpf((1.0f + ei) * (1.0f + eg));
                const float km = __builtin_fmaf(K2, eg, -K2) * r1;  // -2log2e * i*tanh(v_g)
                cs = __builtin_fmaf(fg, cs, km);                    // -2log2e * c
                const float ec = fexp2(cs);                         // e^{-2c}
                const float h  = (1.0f - ec) *
                    __builtin_amdgcn_rcpf((1.0f + eo) * (1.0f + ec));        // o*tanh(c)

                // ---- ring prefetch FIRST (LDS queue: [ring, write, hb x5]) ----
                xp = ring[(t + 1) & (RS - 1)][lane];   // last-iter race benign

                // ---- stage h (unconditional: clamp lanes duplicate lane 19) ----
                hstage[buf][i][hpos] = h;
                __builtin_amdgcn_wave_barrier();

                // ---- broadcast read of own half's 20 h (same-wave LDS in-order) ----
#pragma unroll
                for (int k = 0; k < 5; ++k)
                    hb[k] = *(const f4*)&hstage[buf][i][hboff + 4 * k];
            }
        }

        // ---- final chunk's dump (no trailing barrier needed) ----
        {
            const float* hsrc = &hstage[(NCHUNK - 1) & 1][0][0];
#pragma unroll
            for (int q = 0; q < 20; ++q) {
                out[offd[q]] = hsrc[lds_d[q]];
            }
        }
    }
}

extern "C" void kernel_launch(void* const* d_in, const int* in_sizes, int n_in,
                              void* d_out, int out_size, void* d_ws, size_t ws_size,
                              hipStream_t stream) {
    const float* xp     = (const float*)d_in[0];
    const float* w_ih_f = (const float*)d_in[1];
    const float* w_hh_f = (const float*)d_in[2];
    const float* b_ih_f = (const float*)d_in[3];
    const float* b_hh_f = (const float*)d_in[4];
    const float* w_ih_r = (const float*)d_in[5];
    const float* w_hh_r = (const float*)d_in[6];
    const float* b_ih_r = (const float*)d_in[7];
    const float* b_hh_r = (const float*)d_in[8];
    float* outp = (float*)d_out;

    hipLaunchKernelGGL(lstm_bidir, dim3(512), dim3(128), 0, stream,
                       xp, w_ih_f, w_hh_f, b_ih_f, b_hh_f,
                       w_ih_r, w_hh_r, b_ih_r, b_hh_r, outp);
}

// Round 19
// 446.994 us; speedup vs baseline: 1.0216x; 1.0016x over previous
//
#include <hip/hip_runtime.h>

typedef float f2 __attribute__((ext_vector_type(2)));
typedef float f4 __attribute__((ext_vector_type(4)));

#define TT 2048
#define BB 512
#define II 10
#define HH 20
#define CH 32                 // consumer steps per barrier / history depth
#define RS 64                 // ring slots = 2 chunks (double buffer)
#define NCHUNK (TT / CH)      // 64

#define LOG2E 1.44269504088896340736f

__device__ __forceinline__ float fexp2(float x) {
#if __has_builtin(__builtin_amdgcn_exp2f)
    return __builtin_amdgcn_exp2f(x);
#else
    return exp2f(x);
#endif
}

// One block = 2 waves per SAMPLE (R16 structure; mid-chunk dump placement).
// Wave 0 (consumer): lanes 0..19 scan FORWARD, lanes 32..51 scan REVERSE
//   (lane owns hidden unit j of its dir; all 4 gates per lane). Per step:
//   rec dots from hb -> ring xp applied LATE -> product-rcp activations
//   (4 exp2 + 3 rcp) with cs = -2log2e*c via fma -> h -> ring prefetch ->
//   ds_write h into hstage[chunk&1] -> 5x ds_read broadcast.
//   hstage is double-buffered [2][32][40]; the HBM dump of chunk k-1 sits
//   BETWEEN steps 8 and 9 of chunk k: past the producer's chunk-start ring
//   burst (no DS contention, R18's mistake) and with ~24 steps (~12Kcy) for
//   the 20 stores to retire before the chunk-end barrier -> the barrier's
//   implied vmcnt(0) drain (R16 paid ~300-400cy/chunk) disappears.
//   Clamp lanes (hl 20..31) write the same value as lane 19 (benign race).
// Wave 1 (producer): xproj[t] = b + W_ih x[t] (pre-scaled) into ring[64][64],
//   double-buffered halves, 1 __syncthreads per 32 steps (identical to R16).
__global__ __launch_bounds__(128, 1) void lstm_bidir(
    const float* __restrict__ x,
    const float* __restrict__ w_ih_f, const float* __restrict__ w_hh_f,
    const float* __restrict__ b_ih_f, const float* __restrict__ b_hh_f,
    const float* __restrict__ w_ih_r, const float* __restrict__ w_hh_r,
    const float* __restrict__ b_ih_r, const float* __restrict__ b_hh_r,
    float* __restrict__ out)
{
    const int tid  = threadIdx.x;
    const int wid  = tid >> 6;     // 0 = consumer, 1 = producer
    const int lane = tid & 63;
    const int s    = blockIdx.x;   // batch sample

    const int  dirh  = lane >> 5;          // 0 = forward half, 1 = reverse half
    const int  hl    = lane & 31;
    const bool valid = (hl < HH);
    const int  j     = valid ? hl : (HH - 1);   // clamp keeps loads in-bounds

    const float* __restrict__ w_ih = dirh ? w_ih_r : w_ih_f;
    const float* __restrict__ w_hh = dirh ? w_hh_r : w_hh_f;
    const float* __restrict__ b_ih = dirh ? b_ih_r : b_ih_f;
    const float* __restrict__ b_hh = dirh ? b_hh_r : b_hh_f;

    const int t0    = dirh ? (TT - 1) : 0;
    const int xstep = dirh ? -(BB * II) : (BB * II);
    const int ostep = dirh ? -(BB * 2 * HH) : (BB * 2 * HH);
    const int xbase = (t0 * BB + s) * II;

    // Row scale per gate (i,f,g,o): sigmoid rows -log2e, tanh row -2log2e.
    const float gsc[4] = { -LOG2E, -LOG2E, -2.0f * LOG2E, -LOG2E };

    __shared__ f4    ring[RS][64];           // xproj ring: [slot][lane]
    __shared__ float hstage[2][CH][2 * HH];  // [buf][step][fwd20|rev20]

    if (wid == 1) {
        // ---------------- producer wave (identical to R16) ----------------
        f2 wih[4][5];
        float bs[4];
#pragma unroll
        for (int g = 0; g < 4; ++g) {
            const int r = g * HH + j;
#pragma unroll
            for (int k = 0; k < 5; ++k) {
                f2 w = *(const f2*)(w_ih + r * II + 2 * k);
                wih[g][k] = w * gsc[g];
            }
            bs[g] = (b_ih[r] + b_hh[r]) * gsc[g];
        }

        auto produce8 = [&](int base) {
            f2 xb[8][5];
#pragma unroll
            for (int i = 0; i < 8; ++i) {
                int u = base + i; if (u > TT - 1) u = TT - 1;   // in-bounds clamp
                const float* px = x + (xbase + u * xstep);
#pragma unroll
                for (int k = 0; k < 5; ++k) xb[i][k] = *(const f2*)(px + 2 * k);
            }
#pragma unroll
            for (int i = 0; i < 8; ++i) {
                const int u = base + i;
                if (u < TT) {
                    f4 xp;
#pragma unroll
                    for (int g = 0; g < 4; ++g) {
                        f2 p = {bs[g], 0.f};
#pragma unroll
                        for (int k = 0; k < 5; ++k) p += wih[g][k] * xb[i][k];
                        xp[g] = p[0] + p[1];
                    }
                    ring[u & (RS - 1)][lane] = xp;
                }
            }
        };

        produce8(0);  produce8(8);     // prefill chunk 0
        produce8(16); produce8(24);
        for (int chunk = 0; chunk < NCHUNK; ++chunk) {
            __syncthreads();
            const int base = (chunk + 1) * CH;   // fill next chunk's half
            produce8(base);      produce8(base + 8);
            produce8(base + 16); produce8(base + 24);
        }
    } else {
        // ---------------- consumer wave (two scans, one per half) ----------------
        __builtin_amdgcn_s_setprio(1);

        f2 whh[4][10];
#pragma unroll
        for (int g = 0; g < 4; ++g) {
            const int r = g * HH + j;
#pragma unroll
            for (int k = 0; k < 10; ++k) {
                f2 w = *(const f2*)(w_hh + r * HH + 2 * k);
                whh[g][k] = w * gsc[g];
            }
        }

        const int hpos  = dirh * HH + j;      // own write slot in an hstage row
        const int hboff = dirh * HH;          // own half's 20-float segment

        // Dump mapping: per half, 640 elements (32 t x 20 j) over 32 lanes x 20.
        const int obase = (t0 * BB + s) * (2 * HH) + dirh * HH;
        int offd[20], lds_d[20];
#pragma unroll
        for (int q = 0; q < 20; ++q) {
            const int idx = q * 32 + hl;          // 0..639 within own half
            const int td  = idx / HH;             // 0..31
            const int jd  = idx - td * HH;        // 0..19
            offd[q]  = obase + td * ostep + jd;
            lds_d[q] = td * (2 * HH) + dirh * HH + jd;
        }

        const float K2 = 2.0f * LOG2E;

        f4 hb[5];
#pragma unroll
        for (int k = 0; k < 5; ++k) hb[k] = f4{0.f, 0.f, 0.f, 0.f};

        float cs = 0.0f;    // cs = -2*log2e * c  (so e^{-2c} = 2^cs)
        int t = 0;
        f4 xp;

        // One scan step (both halves in lane-parallel).
        auto step = [&](int i, int buf) {
            // ---- recurrent dots: 4 gates x 10 pk-FMA (hb-dependent only) ----
            f2 a0[4], a1[4];
#pragma unroll
            for (int g = 0; g < 4; ++g) { a0[g] = f2{0.f, 0.f}; a1[g] = f2{0.f, 0.f}; }
#pragma unroll
            for (int k = 0; k < 5; ++k) {
                const f4 hv = hb[k];
                f2 lo; lo[0] = hv[0]; lo[1] = hv[1];
                f2 hi; hi[0] = hv[2]; hi[1] = hv[3];
#pragma unroll
                for (int g = 0; g < 4; ++g) {
                    a0[g] += whh[g][2 * k]     * lo;
                    a1[g] += whh[g][2 * k + 1] * hi;
                }
            }
            // xp applied LATE: ring ds_read gets ~80cy of rec-FMA slack.
            float u[4];
#pragma unroll
            for (int g = 0; g < 4; ++g) {
                const f2 a = a0[g] + a1[g];
                u[g] = (xp[g] + a[0]) + a[1];   // pre-scaled: exp2-ready
            }

            // ---- activations, product-rcp + cs fold (4 exp2 + 3 rcp) ----
            const float ei = fexp2(u[0]);
            const float ef = fexp2(u[1]);
            const float eg = fexp2(u[2]);
            const float eo = fexp2(u[3]);
            const float fg = __builtin_amdgcn_rcpf(1.0f + ef);           // sigma(v_f)
            const float r1 = __builtin_amdgcn_rcpf((1.0f + ei) * (1.0f + eg));
            const float km = __builtin_fmaf(K2, eg, -K2) * r1;  // -2log2e * i*tanh(v_g)
            cs = __builtin_fmaf(fg, cs, km);                    // -2log2e * c
            const float ec = fexp2(cs);                         // e^{-2c}
            const float h  = (1.0f - ec) *
                __builtin_amdgcn_rcpf((1.0f + eo) * (1.0f + ec));        // o*tanh(c)

            // ---- ring prefetch FIRST (LDS queue: [ring, write, hb x5]) ----
            xp = ring[(t + 1) & (RS - 1)][lane];   // last-iter race benign

            // ---- stage h (unconditional: clamp lanes duplicate lane 19) ----
            hstage[buf][i][hpos] = h;
            __builtin_amdgcn_wave_barrier();

            // ---- broadcast read of own half's 20 h (same-wave LDS in-order) ----
#pragma unroll
            for (int k = 0; k < 5; ++k)
                hb[k] = *(const f4*)&hstage[buf][i][hboff + 4 * k];

            ++t;
        };

        for (int chunk = 0; chunk < NCHUNK; ++chunk) {
            __syncthreads();
            const int buf = chunk & 1;
            xp = ring[t & (RS - 1)][lane];   // first step of chunk

#pragma unroll 4
            for (int i = 0; i < 8; ++i) step(i, buf);

            // ---- mid-chunk dump of chunk-1's buffer: past the producer's
            //      ring burst, and ~24 steps for stores to retire before the
            //      barrier (its vmcnt drain vanishes) ----
            if (chunk > 0) {
                const float* hsrc = &hstage[buf ^ 1][0][0];
#pragma unroll
                for (int q = 0; q < 20; ++q) {
                    out[offd[q]] = hsrc[lds_d[q]];
                    offd[q] += CH * ostep;
                }
            }

#pragma unroll 4
            for (int i = 8; i < CH; ++i) step(i, buf);
        }

        // ---- final chunk's dump ----
        {
            const float* hsrc = &hstage[(NCHUNK - 1) & 1][0][0];
#pragma unroll
            for (int q = 0; q < 20; ++q) {
                out[offd[q]] = hsrc[lds_d[q]];
            }
        }
    }
}

extern "C" void kernel_launch(void* const* d_in, const int* in_sizes, int n_in,
                              void* d_out, int out_size, void* d_ws, size_t ws_size,
                              hipStream_t stream) {
    const float* xp     = (const float*)d_in[0];
    const float* w_ih_f = (const float*)d_in[1];
    const float* w_hh_f = (const float*)d_in[2];
    const float* b_ih_f = (const float*)d_in[3];
    const float* b_hh_f = (const float*)d_in[4];
    const float* w_ih_r = (const float*)d_in[5];
    const float* w_hh_r = (const float*)d_in[6];
    const float* b_ih_r = (const float*)d_in[7];
    const float* b_hh_r = (const float*)d_in[8];
    float* outp = (float*)d_out;

    hipLaunchKernelGGL(lstm_bidir, dim3(512), dim3(128), 0, stream,
                       xp, w_ih_f, w_hh_f, b_ih_f, b_hh_f,
                       w_ih_r, w_hh_r, b_ih_r, b_hh_r, outp);
}